// Round 10
// baseline (402.743 us; speedup 1.0000x reference)
//
#include <hip/hip_runtime.h>

typedef __bf16 bf16_t;
typedef bf16_t bf16x4 __attribute__((ext_vector_type(4)));
typedef bf16_t bf16x8 __attribute__((ext_vector_type(8)));
typedef float f32x4 __attribute__((ext_vector_type(4)));
typedef unsigned short u16x8 __attribute__((ext_vector_type(8)));

#define MFMA(a, b, c) __builtin_amdgcn_mfma_f32_16x16x32_bf16(a, b, c, 0, 0, 0)

__device__ inline float exp2_fast(float x) {
  float r;
  asm volatile("v_exp_f32 %0, %1" : "=v"(r) : "v"(x));
  return r;
}

// async global->LDS, 16B/lane; HW dest = wave-uniform base + lane*16
__device__ inline void gll16(const bf16_t* g, bf16_t* l) {
  __builtin_amdgcn_global_load_lds(
      (const __attribute__((address_space(1))) unsigned int*)(g),
      (__attribute__((address_space(3))) unsigned int*)(l), 16, 0, 0);
}

// exact-erf GELU via A&S 7.1.26 poly (|err| < 1.5e-7, invisible under bf16 store)
__device__ inline float gelu_f(float v) {
  float ax = fabsf(v) * 0.70710678118f;
  float t = __builtin_amdgcn_rcpf(1.0f + 0.3275911f * ax);
  float p = ((((1.061405429f * t - 1.453152027f) * t + 1.421413741f) * t -
              0.284496736f) * t + 0.254829592f) * t;
  float e = exp2_fast(-ax * ax * 1.4426950408889634f);
  float erf = 1.0f - p * e;
  erf = v < 0.f ? -erf : erf;
  return 0.5f * v * (1.0f + erf);
}

// ---------------- LayerNorm (fp32 in -> bf16 out), D=1024 ----------------
__global__ __launch_bounds__(256) void ln_kernel(const float* __restrict__ x,
                                                 const float* __restrict__ g,
                                                 const float* __restrict__ b,
                                                 bf16_t* __restrict__ out) {
  long row = blockIdx.x;
  const float4* xr = (const float4*)(x + row * 1024);
  float4 v = xr[threadIdx.x];
  float s = v.x + v.y + v.z + v.w;
  float s2 = v.x * v.x + v.y * v.y + v.z * v.z + v.w * v.w;
#pragma unroll
  for (int m = 32; m >= 1; m >>= 1) {
    s += __shfl_xor(s, m);
    s2 += __shfl_xor(s2, m);
  }
  __shared__ float red[8];
  int wid = threadIdx.x >> 6;
  if ((threadIdx.x & 63) == 0) {
    red[wid] = s;
    red[4 + wid] = s2;
  }
  __syncthreads();
  s = red[0] + red[1] + red[2] + red[3];
  s2 = red[4] + red[5] + red[6] + red[7];
  float mu = s * (1.f / 1024.f);
  float rs = rsqrtf(s2 * (1.f / 1024.f) - mu * mu + 1e-5f);
  float4 gv = ((const float4*)g)[threadIdx.x];
  float4 bv = ((const float4*)b)[threadIdx.x];
  bf16_t o0 = (bf16_t)((v.x - mu) * rs * gv.x + bv.x);
  bf16_t o1 = (bf16_t)((v.y - mu) * rs * gv.y + bv.y);
  bf16_t o2 = (bf16_t)((v.z - mu) * rs * gv.z + bv.z);
  bf16_t o3 = (bf16_t)((v.w - mu) * rs * gv.w + bv.w);
  ushort4 pk;
  pk.x = *(unsigned short*)&o0;
  pk.y = *(unsigned short*)&o1;
  pk.z = *(unsigned short*)&o2;
  pk.w = *(unsigned short*)&o3;
  *(ushort4*)(out + row * 1024 + threadIdx.x * 4) = pk;
}

// ---- fused weight convert+transpose for all 4 weights (one dispatch) ----
__global__ __launch_bounds__(256) void wconv_all(
    const float* __restrict__ qkv_w, bf16_t* __restrict__ qkv_wt,
    const float* __restrict__ proj_w, bf16_t* __restrict__ proj_wt,
    const float* __restrict__ fc1_w, bf16_t* __restrict__ fc1_wt,
    const float* __restrict__ fc2_w, bf16_t* __restrict__ fc2_wt) {
  int id = blockIdx.x;
  const float* W;
  bf16_t* Wt;
  int K, N, bx, by;
  if (id < 768) {
    W = qkv_w; Wt = qkv_wt; K = 1024; N = 3072; bx = id % 48; by = id / 48;
  } else if (id < 1024) {
    int l = id - 768;
    W = proj_w; Wt = proj_wt; K = 1024; N = 1024; bx = l % 16; by = l / 16;
  } else if (id < 2048) {
    int l = id - 1024;
    W = fc1_w; Wt = fc1_wt; K = 1024; N = 4096; bx = l % 64; by = l / 64;
  } else {
    int l = id - 2048;
    W = fc2_w; Wt = fc2_wt; K = 4096; N = 1024; bx = l % 16; by = l / 16;
  }
  __shared__ float t[64][65];
  int n0 = bx * 64, k0 = by * 64;
  int tid = threadIdx.x;
  int c4 = tid & 15;
  int r = tid >> 4;
#pragma unroll
  for (int s = 0; s < 4; s++) {
    int k = r + s * 16;
    float4 v = *(const float4*)(W + (long)(k0 + k) * N + n0 + c4 * 4);
    t[k][c4 * 4] = v.x;
    t[k][c4 * 4 + 1] = v.y;
    t[k][c4 * 4 + 2] = v.z;
    t[k][c4 * 4 + 3] = v.w;
  }
  __syncthreads();
  int n = tid >> 2;
  int kc = (tid & 3) * 16;
  ushort4 pk[4];
#pragma unroll
  for (int c = 0; c < 4; c++) {
#pragma unroll
    for (int j = 0; j < 4; j++) {
      bf16_t x = (bf16_t)t[kc + c * 4 + j][n];
      ((unsigned short*)&pk[c])[j] = *(unsigned short*)&x;
    }
  }
  bf16_t* dst = Wt + (long)(n0 + n) * K + k0 + kc;
#pragma unroll
  for (int c = 0; c < 4; c++) *(ushort4*)(dst + c * 4) = pk[c];
}

// ------- GEMM: 256x128 tile, 512 thr, 3-stage pipe (qkv / proj / fc2) -------
#define STAGE_PTR(DA, DB, k0)                 \
  gll16(ga + (k0), DA + w * 512);             \
  gll16(ga + (k0) + astep, DA + 4096 + w * 512); \
  gll16(gb + (k0), DB + w * 512);

#define COMPUTE(LA, LB)                                                \
  {                                                                    \
    bf16x8 af[4], bfr[4];                                              \
    _Pragma("unroll") for (int mt = 0; mt < 4; mt++) af[mt] =          \
        *(const bf16x8*)(LA + (wm + mt * 16 + l15) * 32 + quad * 8);   \
    _Pragma("unroll") for (int nt = 0; nt < 4; nt++) bfr[nt] =         \
        *(const bf16x8*)(LB + (wn + nt * 16 + l15) * 32 + quad * 8);   \
    _Pragma("unroll") for (int mt = 0; mt < 4; mt++)                   \
        _Pragma("unroll") for (int nt = 0; nt < 4; nt++) acc[mt][nt] = \
            MFMA(af[mt], bfr[nt], acc[mt][nt]);                        \
  }

#define WB3 asm volatile("s_waitcnt vmcnt(3)\ns_barrier" ::: "memory")
#define WB0 asm volatile("s_waitcnt vmcnt(0)\ns_barrier" ::: "memory")

__global__ __launch_bounds__(512, 4) void gemm_kernel(
    const bf16_t* __restrict__ A, const bf16_t* __restrict__ Bt,
    const float* __restrict__ bias, const float* __restrict__ resid,
    void* __restrict__ Cout, int M, int N, int K, int epi) {
  __shared__ bf16_t lA0[256 * 32], lB0[128 * 32];
  __shared__ bf16_t lA1[256 * 32], lB1[128 * 32];
  __shared__ bf16_t lA2[256 * 32], lB2[128 * 32];
  int tid = threadIdx.x;
  int bn = blockIdx.x, bm = blockIdx.y;
  int kchunk = K / gridDim.z;
  int kbeg = blockIdx.z * kchunk, kend = kbeg + kchunk;

  int lane = tid & 63, w = tid >> 6;
  int quad = lane >> 4, l15 = lane & 15;
  int wm = (w & 3) * 64, wn = (w >> 2) * 64;

  f32x4 acc[4][4];
#pragma unroll
  for (int i = 0; i < 4; i++)
#pragma unroll
    for (int j = 0; j < 4; j++) acc[i][j] = (f32x4){0.f, 0.f, 0.f, 0.f};

  const bf16_t* ga = A + (long)(bm * 256 + w * 16 + (lane >> 2)) * K + (lane & 3) * 8;
  const bf16_t* gb = Bt + (long)(bn * 128 + w * 16 + (lane >> 2)) * K + (lane & 3) * 8;
  long astep = (long)128 * K;

  int nit = (kend - kbeg) >> 5;
  bf16_t *A0 = lA0, *A1 = lA1, *A2 = lA2;
  bf16_t *B0 = lB0, *B1 = lB1, *B2 = lB2;
  STAGE_PTR(A0, B0, kbeg);
  STAGE_PTR(A1, B1, kbeg + 32);
  for (int i = 0; i < nit; i++) {
    if (i + 1 < nit) { WB3; } else { WB0; }
    if (i + 2 < nit) {
      int ks = kbeg + (i + 2) * 32;
      STAGE_PTR(A2, B2, ks);
    }
    COMPUTE(A0, B0);
    bf16_t* t;
    t = A0; A0 = A1; A1 = A2; A2 = t;
    t = B0; B0 = B1; B1 = B2; B2 = t;
  }

#pragma unroll
  for (int mt = 0; mt < 4; mt++) {
#pragma unroll
    for (int r = 0; r < 4; r++) {
      long row = bm * 256 + wm + mt * 16 + quad * 4 + r;
#pragma unroll
      for (int nt = 0; nt < 4; nt++) {
        int col = bn * 128 + wn + nt * 16 + l15;
        long idx = row * N + col;
        if (epi == 3) {
          ((bf16_t*)Cout)[(long)blockIdx.z * M * N + idx] = (bf16_t)acc[mt][nt][r];
        } else {
          float v = acc[mt][nt][r] + bias[col];
          if (epi == 1) {
            ((float*)Cout)[idx] = v + resid[idx];
          } else if (epi == 2) {
            ((bf16_t*)Cout)[idx] = (bf16_t)gelu_f(v);
          } else {
            ((bf16_t*)Cout)[idx] = (bf16_t)v;
          }
        }
      }
    }
  }
}

// ------- GEMM 256x256, 512 thr, 1 block/CU, 32 MFMA/wave/barrier (fc1: gelu) -------
#define STAGE256(DA, DB, k0)                  \
  gll16(ga + (k0), DA + w * 512);             \
  gll16(ga + (k0) + astep, DA + 4096 + w * 512); \
  gll16(gb + (k0), DB + w * 512);             \
  gll16(gb + (k0) + astep, DB + 4096 + w * 512);

__global__ __launch_bounds__(512, 2) void gemm256_kernel(
    const bf16_t* __restrict__ A, const bf16_t* __restrict__ Bt,
    const float* __restrict__ bias, void* __restrict__ Cout, int M, int N, int K) {
  __shared__ bf16_t lA0[256 * 32], lB0[256 * 32];
  __shared__ bf16_t lA1[256 * 32], lB1[256 * 32];
  __shared__ bf16_t lA2[256 * 32], lB2[256 * 32];
  int tid = threadIdx.x;
  int bn = blockIdx.x, bm = blockIdx.y;
  int lane = tid & 63, w = tid >> 6;
  int quad = lane >> 4, l15 = lane & 15;
  int wm = (w & 3) * 64, wn = (w >> 2) * 128;

  f32x4 acc[4][8];
#pragma unroll
  for (int i = 0; i < 4; i++)
#pragma unroll
    for (int j = 0; j < 8; j++) acc[i][j] = (f32x4){0.f, 0.f, 0.f, 0.f};

  const bf16_t* ga = A + (long)(bm * 256 + w * 16 + (lane >> 2)) * K + (lane & 3) * 8;
  const bf16_t* gb = Bt + (long)(bn * 256 + w * 16 + (lane >> 2)) * K + (lane & 3) * 8;
  long astep = (long)128 * K;

  int nit = K >> 5;
  bf16_t *A0 = lA0, *A1 = lA1, *A2 = lA2;
  bf16_t *B0 = lB0, *B1 = lB1, *B2 = lB2;
  STAGE256(A0, B0, 0);
  STAGE256(A1, B1, 32);
  for (int i = 0; i < nit; i++) {
    if (i + 1 < nit) {
      asm volatile("s_waitcnt vmcnt(4)\ns_barrier" ::: "memory");
    } else {
      asm volatile("s_waitcnt vmcnt(0)\ns_barrier" ::: "memory");
    }
    if (i + 2 < nit) {
      int ks = (i + 2) * 32;
      STAGE256(A2, B2, ks);
    }
    {
      bf16x8 af[4], bfr[8];
#pragma unroll
      for (int mt = 0; mt < 4; mt++)
        af[mt] = *(const bf16x8*)(A0 + (wm + mt * 16 + l15) * 32 + quad * 8);
#pragma unroll
      for (int nt = 0; nt < 8; nt++)
        bfr[nt] = *(const bf16x8*)(B0 + (wn + nt * 16 + l15) * 32 + quad * 8);
#pragma unroll
      for (int mt = 0; mt < 4; mt++)
#pragma unroll
        for (int nt = 0; nt < 8; nt++) acc[mt][nt] = MFMA(af[mt], bfr[nt], acc[mt][nt]);
    }
    bf16_t* t;
    t = A0; A0 = A1; A1 = A2; A2 = t;
    t = B0; B0 = B1; B1 = B2; B2 = t;
  }

#pragma unroll
  for (int mt = 0; mt < 4; mt++) {
#pragma unroll
    for (int r = 0; r < 4; r++) {
      long row = bm * 256 + wm + mt * 16 + quad * 4 + r;
#pragma unroll
      for (int nt = 0; nt < 8; nt++) {
        int col = bn * 256 + wn + nt * 16 + l15;
        float v = acc[mt][nt][r] + bias[col];
        ((bf16_t*)Cout)[row * N + col] = (bf16_t)gelu_f(v);
      }
    }
  }
}

// ---- fused: x1 = p0..p3+bias+resid ; mb = LayerNorm(x1)*g+b ----
__global__ __launch_bounds__(256) void reduce_ln_kernel(
    const bf16_t* __restrict__ p, const float* __restrict__ bias,
    const float* __restrict__ resid, float* __restrict__ x1,
    const float* __restrict__ g, const float* __restrict__ bb,
    bf16_t* __restrict__ mb) {
  const long MN = (long)4096 * 1024;
  long row = blockIdx.x;
  int t = threadIdx.x;
  bf16x4 a0 = *(const bf16x4*)(p + row * 1024 + t * 4);
  bf16x4 a1 = *(const bf16x4*)(p + MN + row * 1024 + t * 4);
  bf16x4 a2 = *(const bf16x4*)(p + 2 * MN + row * 1024 + t * 4);
  bf16x4 a3 = *(const bf16x4*)(p + 3 * MN + row * 1024 + t * 4);
  float4 r = ((const float4*)(resid + row * 1024))[t];
  float4 bv = ((const float4*)bias)[t];
  float4 v;
  v.x = (float)a0[0] + (float)a1[0] + (float)a2[0] + (float)a3[0] + r.x + bv.x;
  v.y = (float)a0[1] + (float)a1[1] + (float)a2[1] + (float)a3[1] + r.y + bv.y;
  v.z = (float)a0[2] + (float)a1[2] + (float)a2[2] + (float)a3[2] + r.z + bv.z;
  v.w = (float)a0[3] + (float)a1[3] + (float)a2[3] + (float)a3[3] + r.w + bv.w;
  ((float4*)(x1 + row * 1024))[t] = v;
  float s = v.x + v.y + v.z + v.w;
  float s2 = v.x * v.x + v.y * v.y + v.z * v.z + v.w * v.w;
#pragma unroll
  for (int m = 32; m >= 1; m >>= 1) {
    s += __shfl_xor(s, m);
    s2 += __shfl_xor(s2, m);
  }
  __shared__ float red[8];
  int wid = t >> 6;
  if ((t & 63) == 0) {
    red[wid] = s;
    red[4 + wid] = s2;
  }
  __syncthreads();
  s = red[0] + red[1] + red[2] + red[3];
  s2 = red[4] + red[5] + red[6] + red[7];
  float mu = s * (1.f / 1024.f);
  float rs = rsqrtf(s2 * (1.f / 1024.f) - mu * mu + 1e-5f);
  float4 gv = ((const float4*)g)[t];
  float4 b2 = ((const float4*)bb)[t];
  bf16_t o0 = (bf16_t)((v.x - mu) * rs * gv.x + b2.x);
  bf16_t o1 = (bf16_t)((v.y - mu) * rs * gv.y + b2.y);
  bf16_t o2 = (bf16_t)((v.z - mu) * rs * gv.z + b2.z);
  bf16_t o3 = (bf16_t)((v.w - mu) * rs * gv.w + b2.w);
  ushort4 pk;
  pk.x = *(unsigned short*)&o0;
  pk.y = *(unsigned short*)&o1;
  pk.z = *(unsigned short*)&o2;
  pk.w = *(unsigned short*)&o3;
  *(ushort4*)(mb + row * 1024 + t * 4) = pk;
}

// ---- fc2 reduce: out = p0..p3 + bias + resid (fp32) ----
__global__ __launch_bounds__(256) void reduce4_kernel(const bf16_t* __restrict__ p,
                                                      const float* __restrict__ bias,
                                                      const float* __restrict__ resid,
                                                      float* __restrict__ out) {
  long i = (long)blockIdx.x * 256 + threadIdx.x;
  const long MN = (long)4096 * 1024;
  bf16x4 a0 = *(const bf16x4*)(p + i * 4);
  bf16x4 a1 = *(const bf16x4*)(p + MN + i * 4);
  bf16x4 a2 = *(const bf16x4*)(p + 2 * MN + i * 4);
  bf16x4 a3 = *(const bf16x4*)(p + 3 * MN + i * 4);
  float4 r = ((const float4*)resid)[i];
  float4 bv = ((const float4*)bias)[i & 255];
  float4 o;
  o.x = (float)a0[0] + (float)a1[0] + (float)a2[0] + (float)a3[0] + r.x + bv.x;
  o.y = (float)a0[1] + (float)a1[1] + (float)a2[1] + (float)a3[1] + r.y + bv.y;
  o.z = (float)a0[2] + (float)a1[2] + (float)a2[2] + (float)a3[2] + r.z + bv.z;
  o.w = (float)a0[3] + (float)a1[3] + (float)a2[3] + (float)a3[3] + r.w + bv.w;
  ((float4*)out)[i] = o;
}

// ------- Flash attention: 128 q/block, pipelined K/V staging, XCD-swizzled -------
#define LDV 72

__global__ __launch_bounds__(256) void attn_kernel(const bf16_t* __restrict__ qkv,
                                                   bf16_t* __restrict__ o) {
  const int LD = 3072;
  int id = blockIdx.x;
  int within = id >> 3;
  int bh = (id & 7) * 4 + (within >> 4);
  int qt = within & 15;
  int h = bh & 15, b = bh >> 4;

  int tid = threadIdx.x, w = tid >> 6, lane = tid & 63;
  int quad = lane >> 4, l15 = lane & 15;
  int qrow = qt * 128 + w * 32;
  const bf16_t* base = qkv + (long)b * 2048 * LD + h * 64;
  const bf16_t* Qp = base;
  const bf16_t* Kp = base + 1024;
  const bf16_t* Vp = base + 2048;

  __shared__ bf16_t lK[2][64 * 64];
  __shared__ bf16_t lV[2][64 * LDV];
  __shared__ bf16_t lP[4][32 * LDV];
  bf16_t* myp = lP[w];

  const bf16_t* kg =
      Kp + (long)(w * 16 + (lane >> 3)) * LD + (((lane & 7) ^ (lane >> 3)) & 7) * 8;
  int kk = tid & 31;
  int d0 = (tid >> 5) * 8;
  const bf16_t* vg = Vp + (long)(2 * kk) * LD + d0;

  gll16(kg, lK[0] + w * 1024);
  gll16(kg + 8 * (long)LD, lK[0] + w * 1024 + 512);
  u16x8 va = *(const u16x8*)(vg);
  u16x8 vb = *(const u16x8*)(vg + LD);

  // Q fragments pre-scaled by 0.125*log2(e): exp becomes a bare exp2 of the MFMA score
  const float c2 = 0.18033688011112042f;
  bf16x8 qf[2][2];
#pragma unroll
  for (int qi = 0; qi < 2; qi++)
#pragma unroll
    for (int d = 0; d < 2; d++) {
      bf16x8 q0 =
          *(const bf16x8*)(Qp + (long)(qrow + qi * 16 + l15) * LD + d * 32 + quad * 8);
#pragma unroll
      for (int j = 0; j < 8; j++) qf[qi][d][j] = (bf16_t)((float)q0[j] * c2);
    }

  f32x4 oacc[2][4];
#pragma unroll
  for (int qi = 0; qi < 2; qi++)
#pragma unroll
    for (int t = 0; t < 4; t++) oacc[qi][t] = (f32x4){0.f, 0.f, 0.f, 0.f};
  float li_p[2][4] = {{0.f, 0.f, 0.f, 0.f}, {0.f, 0.f, 0.f, 0.f}};

  int sw0 = (quad ^ l15) & 7;
  int sw1 = ((quad + 4) ^ l15) & 7;

  for (int it = 0; it < 32; it++) {
    int cur = it & 1, nxt = cur ^ 1;
    asm volatile("s_waitcnt vmcnt(0)\ns_barrier" ::: "memory");
    unsigned int* lvw = (unsigned int*)lV[cur];
#pragma unroll
    for (int j = 0; j < 8; j++)
      lvw[(d0 + j) * (LDV / 2) + kk] = (unsigned int)va[j] | ((unsigned int)vb[j] << 16);
    u16x8 va_n = va, vb_n = vb;
    if (it + 1 < 32) {
      long koff2 = (long)(it + 1) * 64 * LD;
      gll16(kg + koff2, lK[nxt] + w * 1024);
      gll16(kg + koff2 + 8 * (long)LD, lK[nxt] + w * 1024 + 512);
      va_n = *(const u16x8*)(vg + koff2);
      vb_n = *(const u16x8*)(vg + koff2 + LD);
    }
    asm volatile("s_waitcnt lgkmcnt(0)\ns_barrier" ::: "memory");

    bf16x8 kf[4][2];
#pragma unroll
    for (int st = 0; st < 4; st++) {
      const bf16_t* krow = lK[cur] + (st * 16 + l15) * 64;
      kf[st][0] = *(const bf16x8*)(krow + sw0 * 8);
      kf[st][1] = *(const bf16x8*)(krow + sw1 * 8);
    }
    f32x4 s[2][4];
#pragma unroll
    for (int qi = 0; qi < 2; qi++)
#pragma unroll
      for (int st = 0; st < 4; st++) {
        f32x4 z = (f32x4){0.f, 0.f, 0.f, 0.f};
        z = MFMA(qf[qi][0], kf[st][0], z);
        s[qi][st] = MFMA(qf[qi][1], kf[st][1], z);
      }

#pragma unroll
    for (int qi = 0; qi < 2; qi++)
#pragma unroll
      for (int st = 0; st < 4; st++)
#pragma unroll
        for (int r = 0; r < 4; r++) {
          float p = exp2_fast(s[qi][st][r]);
          s[qi][st][r] = p;
          li_p[qi][r] += p;
        }

#pragma unroll
    for (int qi = 0; qi < 2; qi++)
#pragma unroll
      for (int r = 0; r < 4; r++)
#pragma unroll
        for (int st = 0; st < 4; st++)
          myp[(qi * 16 + quad * 4 + r) * LDV + st * 16 + l15] = (bf16_t)s[qi][st][r];
    asm volatile("s_waitcnt lgkmcnt(0)" ::: "memory");

    bf16x8 pa[2][2];
#pragma unroll
    for (int qi = 0; qi < 2; qi++) {
      pa[qi][0] = *(const bf16x8*)(myp + (qi * 16 + l15) * LDV + quad * 8);
      pa[qi][1] = *(const bf16x8*)(myp + (qi * 16 + l15) * LDV + 32 + quad * 8);
    }
#pragma unroll
    for (int t = 0; t < 4; t++) {
      const bf16_t* vr = lV[cur] + (t * 16 + l15) * LDV + quad * 8;
      bf16x8 v0 = *(const bf16x8*)(vr);
      bf16x8 v1 = *(const bf16x8*)(vr + 32);
#pragma unroll
      for (int qi = 0; qi < 2; qi++) {
        oacc[qi][t] = MFMA(pa[qi][0], v0, oacc[qi][t]);
        oacc[qi][t] = MFMA(pa[qi][1], v1, oacc[qi][t]);
      }
    }
    va = va_n;
    vb = vb_n;
  }

#pragma unroll
  for (int qi = 0; qi < 2; qi++) {
    float li[4];
#pragma unroll
    for (int r = 0; r < 4; r++) {
      float s = li_p[qi][r];
#pragma unroll
      for (int x = 8; x >= 1; x >>= 1) s += __shfl_xor(s, x);
      li[r] = s;
    }
#pragma unroll
    for (int t = 0; t < 4; t++)
#pragma unroll
      for (int r = 0; r < 4; r++) {
        long q = qrow + qi * 16 + quad * 4 + r;
        o[((long)b * 2048 + q) * 1024 + h * 64 + t * 16 + l15] =
            (bf16_t)(oacc[qi][t][r] / li[r]);
      }
  }
}

extern "C" void kernel_launch(void* const* d_in, const int* in_sizes, int n_in,
                              void* d_out, int out_size, void* d_ws, size_t ws_size,
                              hipStream_t stream) {
  (void)in_sizes; (void)n_in; (void)out_size; (void)ws_size;
  const float* x = (const float*)d_in[0];
  const float* ln1_g = (const float*)d_in[1];
  const float* ln1_b = (const float*)d_in[2];
  const float* lnm_g = (const float*)d_in[3];
  const float* lnm_b = (const float*)d_in[4];
  const float* qkv_w = (const float*)d_in[5];
  const float* qkv_b = (const float*)d_in[6];
  const float* proj_w = (const float*)d_in[7];
  const float* proj_b = (const float*)d_in[8];
  const float* fc1_w = (const float*)d_in[9];
  const float* fc1_b = (const float*)d_in[10];
  const float* fc2_w = (const float*)d_in[11];
  const float* fc2_b = (const float*)d_in[12];
  float* out = (float*)d_out;

  const int M = 4096;
  const int D_ = 1024, MLP_ = 4096, QKV = 3072;

  char* ws = (char*)d_ws;
  bf16_t* h = (bf16_t*)(ws);
  bf16_t* qkvb = (bf16_t*)(ws + (8u << 20));
  bf16_t* ob = (bf16_t*)(ws + (32u << 20));
  float* x1 = (float*)(ws + (40u << 20));
  bf16_t* mb = (bf16_t*)(ws + (56u << 20));
  bf16_t* gb = (bf16_t*)(ws + (64u << 20));
  bf16_t* qkv_wt = (bf16_t*)(ws + (96u << 20));
  bf16_t* proj_wt = (bf16_t*)(ws + (102u << 20));
  bf16_t* fc1_wt = (bf16_t*)(ws + (104u << 20));
  bf16_t* fc2_wt = (bf16_t*)(ws + (112u << 20));
  bf16_t* p_proj = (bf16_t*)(ws);
  bf16_t* p_fc2 = (bf16_t*)(ws);

  wconv_all<<<3072, 256, 0, stream>>>(qkv_w, qkv_wt, proj_w, proj_wt, fc1_w, fc1_wt,
                                      fc2_w, fc2_wt);

  ln_kernel<<<M, 256, 0, stream>>>(x, ln1_g, ln1_b, h);
  gemm_kernel<<<dim3(QKV / 128, M / 256), 512, 0, stream>>>(h, qkv_wt, qkv_b, nullptr,
                                                            qkvb, M, QKV, D_, 0);
  attn_kernel<<<512, 256, 0, stream>>>(qkvb, ob);
  gemm_kernel<<<dim3(D_ / 128, M / 256, 4), 512, 0, stream>>>(ob, proj_wt, nullptr,
                                                              nullptr, p_proj, M, D_,
                                                              D_, 3);
  reduce_ln_kernel<<<M, 256, 0, stream>>>(p_proj, proj_b, x, x1, lnm_g, lnm_b, mb);
  // fc1: 256x256 tile experiment (1 block/CU, 2x MFMA per barrier window)
  gemm256_kernel<<<dim3(MLP_ / 256, M / 256), 512, 0, stream>>>(mb, fc1_wt, fc1_b, gb,
                                                                M, MLP_, D_);
  gemm_kernel<<<dim3(D_ / 128, M / 256, 4), 512, 0, stream>>>(gb, fc2_wt, nullptr,
                                                              nullptr, p_fc2, M, D_,
                                                              MLP_, 3);
  reduce4_kernel<<<4096, 256, 0, stream>>>(p_fc2, fc2_b, x1, out);
}

// Round 11
// 390.900 us; speedup vs baseline: 1.0303x; 1.0303x over previous
//
#include <hip/hip_runtime.h>

typedef __bf16 bf16_t;
typedef bf16_t bf16x4 __attribute__((ext_vector_type(4)));
typedef bf16_t bf16x8 __attribute__((ext_vector_type(8)));
typedef float f32x4 __attribute__((ext_vector_type(4)));
typedef unsigned short u16x8 __attribute__((ext_vector_type(8)));

#define MFMA(a, b, c) __builtin_amdgcn_mfma_f32_16x16x32_bf16(a, b, c, 0, 0, 0)

__device__ inline float exp2_fast(float x) {
  float r;
  asm volatile("v_exp_f32 %0, %1" : "=v"(r) : "v"(x));
  return r;
}

// async global->LDS, 16B/lane; HW dest = wave-uniform base + lane*16
__device__ inline void gll16(const bf16_t* g, bf16_t* l) {
  __builtin_amdgcn_global_load_lds(
      (const __attribute__((address_space(1))) unsigned int*)(g),
      (__attribute__((address_space(3))) unsigned int*)(l), 16, 0, 0);
}

// exact-erf GELU via A&S 7.1.26 poly (|err| < 1.5e-7, invisible under bf16 store)
__device__ inline float gelu_f(float v) {
  float ax = fabsf(v) * 0.70710678118f;
  float t = __builtin_amdgcn_rcpf(1.0f + 0.3275911f * ax);
  float p = ((((1.061405429f * t - 1.453152027f) * t + 1.421413741f) * t -
              0.284496736f) * t + 0.254829592f) * t;
  float e = exp2_fast(-ax * ax * 1.4426950408889634f);
  float erf = 1.0f - p * e;
  erf = v < 0.f ? -erf : erf;
  return 0.5f * v * (1.0f + erf);
}

// ---- fused: weight convert+transpose (blocks 0..3071) + LayerNorm1 (3072..7167) ----
__global__ __launch_bounds__(256) void wconv_all(
    const float* __restrict__ qkv_w, bf16_t* __restrict__ qkv_wt,
    const float* __restrict__ proj_w, bf16_t* __restrict__ proj_wt,
    const float* __restrict__ fc1_w, bf16_t* __restrict__ fc1_wt,
    const float* __restrict__ fc2_w, bf16_t* __restrict__ fc2_wt,
    const float* __restrict__ x, const float* __restrict__ g1,
    const float* __restrict__ b1, bf16_t* __restrict__ h) {
  int id = blockIdx.x;
  if (id >= 3072) {
    // ---- LayerNorm row ----
    long row = id - 3072;
    const float4* xr = (const float4*)(x + row * 1024);
    float4 v = xr[threadIdx.x];
    float s = v.x + v.y + v.z + v.w;
    float s2 = v.x * v.x + v.y * v.y + v.z * v.z + v.w * v.w;
#pragma unroll
    for (int m = 32; m >= 1; m >>= 1) {
      s += __shfl_xor(s, m);
      s2 += __shfl_xor(s2, m);
    }
    __shared__ float red[8];
    int wid = threadIdx.x >> 6;
    if ((threadIdx.x & 63) == 0) {
      red[wid] = s;
      red[4 + wid] = s2;
    }
    __syncthreads();
    s = red[0] + red[1] + red[2] + red[3];
    s2 = red[4] + red[5] + red[6] + red[7];
    float mu = s * (1.f / 1024.f);
    float rs = rsqrtf(s2 * (1.f / 1024.f) - mu * mu + 1e-5f);
    float4 gv = ((const float4*)g1)[threadIdx.x];
    float4 bv = ((const float4*)b1)[threadIdx.x];
    bf16_t o0 = (bf16_t)((v.x - mu) * rs * gv.x + bv.x);
    bf16_t o1 = (bf16_t)((v.y - mu) * rs * gv.y + bv.y);
    bf16_t o2 = (bf16_t)((v.z - mu) * rs * gv.z + bv.z);
    bf16_t o3 = (bf16_t)((v.w - mu) * rs * gv.w + bv.w);
    ushort4 pk;
    pk.x = *(unsigned short*)&o0;
    pk.y = *(unsigned short*)&o1;
    pk.z = *(unsigned short*)&o2;
    pk.w = *(unsigned short*)&o3;
    *(ushort4*)(h + row * 1024 + threadIdx.x * 4) = pk;
    return;
  }
  const float* W;
  bf16_t* Wt;
  int K, N, bx, by;
  if (id < 768) {
    W = qkv_w; Wt = qkv_wt; K = 1024; N = 3072; bx = id % 48; by = id / 48;
  } else if (id < 1024) {
    int l = id - 768;
    W = proj_w; Wt = proj_wt; K = 1024; N = 1024; bx = l % 16; by = l / 16;
  } else if (id < 2048) {
    int l = id - 1024;
    W = fc1_w; Wt = fc1_wt; K = 1024; N = 4096; bx = l % 64; by = l / 64;
  } else {
    int l = id - 2048;
    W = fc2_w; Wt = fc2_wt; K = 4096; N = 1024; bx = l % 16; by = l / 16;
  }
  __shared__ float t[64][65];
  int n0 = bx * 64, k0 = by * 64;
  int tid = threadIdx.x;
  int c4 = tid & 15;
  int r = tid >> 4;
#pragma unroll
  for (int s = 0; s < 4; s++) {
    int k = r + s * 16;
    float4 v = *(const float4*)(W + (long)(k0 + k) * N + n0 + c4 * 4);
    t[k][c4 * 4] = v.x;
    t[k][c4 * 4 + 1] = v.y;
    t[k][c4 * 4 + 2] = v.z;
    t[k][c4 * 4 + 3] = v.w;
  }
  __syncthreads();
  int n = tid >> 2;
  int kc = (tid & 3) * 16;
  ushort4 pk[4];
#pragma unroll
  for (int c = 0; c < 4; c++) {
#pragma unroll
    for (int j = 0; j < 4; j++) {
      bf16_t xq = (bf16_t)t[kc + c * 4 + j][n];
      ((unsigned short*)&pk[c])[j] = *(unsigned short*)&xq;
    }
  }
  bf16_t* dst = Wt + (long)(n0 + n) * K + k0 + kc;
#pragma unroll
  for (int c = 0; c < 4; c++) *(ushort4*)(dst + c * 4) = pk[c];
}

// ------- GEMM: 256x128 tile, 512 thr, 3-stage pipe -------
// epi 0: bf16 = acc+bias ; 1: f32 = acc+bias+resid ; 2: bf16 = gelu(acc+bias)
// epi 3: bf16 partial = acc (split-K chunk blockIdx.z)
#define STAGE_PTR(DA, DB, k0)                 \
  gll16(ga + (k0), DA + w * 512);             \
  gll16(ga + (k0) + astep, DA + 4096 + w * 512); \
  gll16(gb + (k0), DB + w * 512);

#define COMPUTE(LA, LB)                                                \
  {                                                                    \
    bf16x8 af[4], bfr[4];                                              \
    _Pragma("unroll") for (int mt = 0; mt < 4; mt++) af[mt] =          \
        *(const bf16x8*)(LA + (wm + mt * 16 + l15) * 32 + quad * 8);   \
    _Pragma("unroll") for (int nt = 0; nt < 4; nt++) bfr[nt] =         \
        *(const bf16x8*)(LB + (wn + nt * 16 + l15) * 32 + quad * 8);   \
    _Pragma("unroll") for (int mt = 0; mt < 4; mt++)                   \
        _Pragma("unroll") for (int nt = 0; nt < 4; nt++) acc[mt][nt] = \
            MFMA(af[mt], bfr[nt], acc[mt][nt]);                        \
  }

#define WB3 asm volatile("s_waitcnt vmcnt(3)\ns_barrier" ::: "memory")
#define WB0 asm volatile("s_waitcnt vmcnt(0)\ns_barrier" ::: "memory")

__global__ __launch_bounds__(512, 4) void gemm_kernel(
    const bf16_t* __restrict__ A, const bf16_t* __restrict__ Bt,
    const float* __restrict__ bias, const float* __restrict__ resid,
    void* __restrict__ Cout, int M, int N, int K, int epi) {
  __shared__ bf16_t lA0[256 * 32], lB0[128 * 32];
  __shared__ bf16_t lA1[256 * 32], lB1[128 * 32];
  __shared__ bf16_t lA2[256 * 32], lB2[128 * 32];
  int tid = threadIdx.x;
  int bn = blockIdx.x, bm = blockIdx.y;
  int kchunk = K / gridDim.z;
  int kbeg = blockIdx.z * kchunk, kend = kbeg + kchunk;

  int lane = tid & 63, w = tid >> 6;
  int quad = lane >> 4, l15 = lane & 15;
  int wm = (w & 3) * 64, wn = (w >> 2) * 64;

  f32x4 acc[4][4];
#pragma unroll
  for (int i = 0; i < 4; i++)
#pragma unroll
    for (int j = 0; j < 4; j++) acc[i][j] = (f32x4){0.f, 0.f, 0.f, 0.f};

  const bf16_t* ga = A + (long)(bm * 256 + w * 16 + (lane >> 2)) * K + (lane & 3) * 8;
  const bf16_t* gb = Bt + (long)(bn * 128 + w * 16 + (lane >> 2)) * K + (lane & 3) * 8;
  long astep = (long)128 * K;

  int nit = (kend - kbeg) >> 5;
  bf16_t *A0 = lA0, *A1 = lA1, *A2 = lA2;
  bf16_t *B0 = lB0, *B1 = lB1, *B2 = lB2;
  STAGE_PTR(A0, B0, kbeg);
  STAGE_PTR(A1, B1, kbeg + 32);
  for (int i = 0; i < nit; i++) {
    if (i + 1 < nit) { WB3; } else { WB0; }
    if (i + 2 < nit) {
      int ks = kbeg + (i + 2) * 32;
      STAGE_PTR(A2, B2, ks);
    }
    COMPUTE(A0, B0);
    bf16_t* t;
    t = A0; A0 = A1; A1 = A2; A2 = t;
    t = B0; B0 = B1; B1 = B2; B2 = t;
  }

#pragma unroll
  for (int mt = 0; mt < 4; mt++) {
#pragma unroll
    for (int r = 0; r < 4; r++) {
      long row = bm * 256 + wm + mt * 16 + quad * 4 + r;
#pragma unroll
      for (int nt = 0; nt < 4; nt++) {
        int col = bn * 128 + wn + nt * 16 + l15;
        long idx = row * N + col;
        if (epi == 3) {
          ((bf16_t*)Cout)[(long)blockIdx.z * M * N + idx] = (bf16_t)acc[mt][nt][r];
        } else {
          float v = acc[mt][nt][r] + bias[col];
          if (epi == 1) {
            ((float*)Cout)[idx] = v + resid[idx];
          } else if (epi == 2) {
            ((bf16_t*)Cout)[idx] = (bf16_t)gelu_f(v);
          } else {
            ((bf16_t*)Cout)[idx] = (bf16_t)v;
          }
        }
      }
    }
  }
}

// ---- fused: x1 = p0..p3+bias+resid ; mb = LayerNorm(x1)*g+b ----
__global__ __launch_bounds__(256) void reduce_ln_kernel(
    const bf16_t* __restrict__ p, const float* __restrict__ bias,
    const float* __restrict__ resid, float* __restrict__ x1,
    const float* __restrict__ g, const float* __restrict__ bb,
    bf16_t* __restrict__ mb) {
  const long MN = (long)4096 * 1024;
  long row = blockIdx.x;
  int t = threadIdx.x;
  bf16x4 a0 = *(const bf16x4*)(p + row * 1024 + t * 4);
  bf16x4 a1 = *(const bf16x4*)(p + MN + row * 1024 + t * 4);
  bf16x4 a2 = *(const bf16x4*)(p + 2 * MN + row * 1024 + t * 4);
  bf16x4 a3 = *(const bf16x4*)(p + 3 * MN + row * 1024 + t * 4);
  float4 r = ((const float4*)(resid + row * 1024))[t];
  float4 bv = ((const float4*)bias)[t];
  float4 v;
  v.x = (float)a0[0] + (float)a1[0] + (float)a2[0] + (float)a3[0] + r.x + bv.x;
  v.y = (float)a0[1] + (float)a1[1] + (float)a2[1] + (float)a3[1] + r.y + bv.y;
  v.z = (float)a0[2] + (float)a1[2] + (float)a2[2] + (float)a3[2] + r.z + bv.z;
  v.w = (float)a0[3] + (float)a1[3] + (float)a2[3] + (float)a3[3] + r.w + bv.w;
  ((float4*)(x1 + row * 1024))[t] = v;
  float s = v.x + v.y + v.z + v.w;
  float s2 = v.x * v.x + v.y * v.y + v.z * v.z + v.w * v.w;
#pragma unroll
  for (int m = 32; m >= 1; m >>= 1) {
    s += __shfl_xor(s, m);
    s2 += __shfl_xor(s2, m);
  }
  __shared__ float red[8];
  int wid = t >> 6;
  if ((t & 63) == 0) {
    red[wid] = s;
    red[4 + wid] = s2;
  }
  __syncthreads();
  s = red[0] + red[1] + red[2] + red[3];
  s2 = red[4] + red[5] + red[6] + red[7];
  float mu = s * (1.f / 1024.f);
  float rs = rsqrtf(s2 * (1.f / 1024.f) - mu * mu + 1e-5f);
  float4 gv = ((const float4*)g)[t];
  float4 b2 = ((const float4*)bb)[t];
  bf16_t o0 = (bf16_t)((v.x - mu) * rs * gv.x + b2.x);
  bf16_t o1 = (bf16_t)((v.y - mu) * rs * gv.y + b2.y);
  bf16_t o2 = (bf16_t)((v.z - mu) * rs * gv.z + b2.z);
  bf16_t o3 = (bf16_t)((v.w - mu) * rs * gv.w + b2.w);
  ushort4 pk;
  pk.x = *(unsigned short*)&o0;
  pk.y = *(unsigned short*)&o1;
  pk.z = *(unsigned short*)&o2;
  pk.w = *(unsigned short*)&o3;
  *(ushort4*)(mb + row * 1024 + t * 4) = pk;
}

// ---- fc2 reduce: out = p0..p3 + bias + resid (fp32) ----
__global__ __launch_bounds__(256) void reduce4_kernel(const bf16_t* __restrict__ p,
                                                      const float* __restrict__ bias,
                                                      const float* __restrict__ resid,
                                                      float* __restrict__ out) {
  long i = (long)blockIdx.x * 256 + threadIdx.x;
  const long MN = (long)4096 * 1024;
  bf16x4 a0 = *(const bf16x4*)(p + i * 4);
  bf16x4 a1 = *(const bf16x4*)(p + MN + i * 4);
  bf16x4 a2 = *(const bf16x4*)(p + 2 * MN + i * 4);
  bf16x4 a3 = *(const bf16x4*)(p + 3 * MN + i * 4);
  float4 r = ((const float4*)resid)[i];
  float4 bv = ((const float4*)bias)[i & 255];
  float4 o;
  o.x = (float)a0[0] + (float)a1[0] + (float)a2[0] + (float)a3[0] + r.x + bv.x;
  o.y = (float)a0[1] + (float)a1[1] + (float)a2[1] + (float)a3[1] + r.y + bv.y;
  o.z = (float)a0[2] + (float)a1[2] + (float)a2[2] + (float)a3[2] + r.z + bv.z;
  o.w = (float)a0[3] + (float)a1[3] + (float)a2[3] + (float)a3[3] + r.w + bv.w;
  ((float4*)out)[i] = o;
}

// ------- Flash attention, key-split ks=2: 128 q/block, 1024 keys/block -------
// Unnormalized fp32 O-partials + per-row li; merged by attn_merge. 3 blocks/CU.
#define LDV 72

__global__ __launch_bounds__(256) void attn_kernel(const bf16_t* __restrict__ qkv,
                                                   float* __restrict__ oa,
                                                   float* __restrict__ li_g) {
  const int LD = 3072;
  // XCD swizzle: id&7 -> XCD; 4 (b,h) KV sets per XCD; ks innermost
  int id = blockIdx.x;            // 1024 blocks
  int within = id >> 3;           // 0..127
  int bh = (id & 7) * 4 + (within >> 5);
  int local = within & 31;
  int qt = local >> 1;
  int ks = local & 1;
  int h = bh & 15, b = bh >> 4;

  int tid = threadIdx.x, w = tid >> 6, lane = tid & 63;
  int quad = lane >> 4, l15 = lane & 15;
  int qrow = qt * 128 + w * 32;
  const bf16_t* base = qkv + (long)b * 2048 * LD + h * 64;
  const bf16_t* Qp = base;
  const bf16_t* Kp = base + 1024 + (long)ks * 1024 * LD;  // this block's key half
  const bf16_t* Vp = base + 2048 + (long)ks * 1024 * LD;

  __shared__ bf16_t lK[2][64 * 64];
  __shared__ bf16_t lV[2][64 * LDV];
  __shared__ bf16_t lP[4][32 * LDV];
  bf16_t* myp = lP[w];

  const bf16_t* kg =
      Kp + (long)(w * 16 + (lane >> 3)) * LD + (((lane & 7) ^ (lane >> 3)) & 7) * 8;
  int kk = tid & 31;
  int d0 = (tid >> 5) * 8;
  const bf16_t* vg = Vp + (long)(2 * kk) * LD + d0;

  gll16(kg, lK[0] + w * 1024);
  gll16(kg + 8 * (long)LD, lK[0] + w * 1024 + 512);
  u16x8 va = *(const u16x8*)(vg);
  u16x8 vb = *(const u16x8*)(vg + LD);

  // Q pre-scaled by 0.125*log2(e): softmax exp becomes bare exp2 of the score
  const float c2 = 0.18033688011112042f;
  bf16x8 qf[2][2];
#pragma unroll
  for (int qi = 0; qi < 2; qi++)
#pragma unroll
    for (int d = 0; d < 2; d++) {
      bf16x8 q0 =
          *(const bf16x8*)(Qp + (long)(qrow + qi * 16 + l15) * LD + d * 32 + quad * 8);
#pragma unroll
      for (int j = 0; j < 8; j++) qf[qi][d][j] = (bf16_t)((float)q0[j] * c2);
    }

  f32x4 oacc[2][4];
#pragma unroll
  for (int qi = 0; qi < 2; qi++)
#pragma unroll
    for (int t = 0; t < 4; t++) oacc[qi][t] = (f32x4){0.f, 0.f, 0.f, 0.f};
  float li_p[2][4] = {{0.f, 0.f, 0.f, 0.f}, {0.f, 0.f, 0.f, 0.f}};

  int sw0 = (quad ^ l15) & 7;
  int sw1 = ((quad + 4) ^ l15) & 7;

  for (int it = 0; it < 16; it++) {
    int cur = it & 1, nxt = cur ^ 1;
    asm volatile("s_waitcnt vmcnt(0)\ns_barrier" ::: "memory");
    unsigned int* lvw = (unsigned int*)lV[cur];
#pragma unroll
    for (int j = 0; j < 8; j++)
      lvw[(d0 + j) * (LDV / 2) + kk] = (unsigned int)va[j] | ((unsigned int)vb[j] << 16);
    u16x8 va_n = va, vb_n = vb;
    if (it + 1 < 16) {
      long koff2 = (long)(it + 1) * 64 * LD;
      gll16(kg + koff2, lK[nxt] + w * 1024);
      gll16(kg + koff2 + 8 * (long)LD, lK[nxt] + w * 1024 + 512);
      va_n = *(const u16x8*)(vg + koff2);
      vb_n = *(const u16x8*)(vg + koff2 + LD);
    }
    asm volatile("s_waitcnt lgkmcnt(0)\ns_barrier" ::: "memory");

    bf16x8 kf[4][2];
#pragma unroll
    for (int st = 0; st < 4; st++) {
      const bf16_t* krow = lK[cur] + (st * 16 + l15) * 64;
      kf[st][0] = *(const bf16x8*)(krow + sw0 * 8);
      kf[st][1] = *(const bf16x8*)(krow + sw1 * 8);
    }
    f32x4 s[2][4];
#pragma unroll
    for (int qi = 0; qi < 2; qi++)
#pragma unroll
      for (int st = 0; st < 4; st++) {
        f32x4 z = (f32x4){0.f, 0.f, 0.f, 0.f};
        z = MFMA(qf[qi][0], kf[st][0], z);
        s[qi][st] = MFMA(qf[qi][1], kf[st][1], z);
      }

#pragma unroll
    for (int qi = 0; qi < 2; qi++)
#pragma unroll
      for (int st = 0; st < 4; st++)
#pragma unroll
        for (int r = 0; r < 4; r++) {
          float p = exp2_fast(s[qi][st][r]);
          s[qi][st][r] = p;
          li_p[qi][r] += p;
        }

#pragma unroll
    for (int qi = 0; qi < 2; qi++)
#pragma unroll
      for (int r = 0; r < 4; r++)
#pragma unroll
        for (int st = 0; st < 4; st++)
          myp[(qi * 16 + quad * 4 + r) * LDV + st * 16 + l15] = (bf16_t)s[qi][st][r];
    asm volatile("s_waitcnt lgkmcnt(0)" ::: "memory");

    bf16x8 pa[2][2];
#pragma unroll
    for (int qi = 0; qi < 2; qi++) {
      pa[qi][0] = *(const bf16x8*)(myp + (qi * 16 + l15) * LDV + quad * 8);
      pa[qi][1] = *(const bf16x8*)(myp + (qi * 16 + l15) * LDV + 32 + quad * 8);
    }
#pragma unroll
    for (int t = 0; t < 4; t++) {
      const bf16_t* vr = lV[cur] + (t * 16 + l15) * LDV + quad * 8;
      bf16x8 v0 = *(const bf16x8*)(vr);
      bf16x8 v1 = *(const bf16x8*)(vr + 32);
#pragma unroll
      for (int qi = 0; qi < 2; qi++) {
        oacc[qi][t] = MFMA(pa[qi][0], v0, oacc[qi][t]);
        oacc[qi][t] = MFMA(pa[qi][1], v1, oacc[qi][t]);
      }
    }
    va = va_n;
    vb = vb_n;
  }

  // store unnormalized partials + li (reduced over the 16 l15 lanes)
  float* oap = oa + (long)ks * 4096 * 1024;
#pragma unroll
  for (int qi = 0; qi < 2; qi++) {
    float li[4];
#pragma unroll
    for (int r = 0; r < 4; r++) {
      float s = li_p[qi][r];
#pragma unroll
      for (int x = 8; x >= 1; x >>= 1) s += __shfl_xor(s, x);
      li[r] = s;
    }
    if (l15 == 0) {
      long q = qrow + qi * 16 + quad * 4;
      float4 lv = {li[0], li[1], li[2], li[3]};
      *(float4*)(li_g + ((long)ks * 32 + b * 16 + h) * 2048 + q) = lv;
    }
#pragma unroll
    for (int t = 0; t < 4; t++)
#pragma unroll
      for (int r = 0; r < 4; r++) {
        long q = qrow + qi * 16 + quad * 4 + r;
        oap[((long)b * 2048 + q) * 1024 + h * 64 + t * 16 + l15] = oacc[qi][t][r];
      }
  }
}

// ---- merge the two key-halves: ob = (oa0+oa1) / (l0+l1), bf16 ----
__global__ __launch_bounds__(256) void attn_merge(const float* __restrict__ oa,
                                                  const float* __restrict__ li_g,
                                                  bf16_t* __restrict__ ob) {
  const long MN = (long)4096 * 1024;
  long row = blockIdx.x;  // b*2048 + q
  int t = threadIdx.x;
  int b = (int)(row >> 11);
  int q = (int)(row & 2047);
  int h = (t * 4) >> 6;
  float l0 = li_g[((long)b * 16 + h) * 2048 + q];
  float l1 = li_g[((long)32 + b * 16 + h) * 2048 + q];
  float inv = 1.0f / (l0 + l1);
  float4 a = ((const float4*)(oa + row * 1024))[t];
  float4 c = ((const float4*)(oa + MN + row * 1024))[t];
  bf16_t o0 = (bf16_t)((a.x + c.x) * inv);
  bf16_t o1 = (bf16_t)((a.y + c.y) * inv);
  bf16_t o2 = (bf16_t)((a.z + c.z) * inv);
  bf16_t o3 = (bf16_t)((a.w + c.w) * inv);
  ushort4 pk;
  pk.x = *(unsigned short*)&o0;
  pk.y = *(unsigned short*)&o1;
  pk.z = *(unsigned short*)&o2;
  pk.w = *(unsigned short*)&o3;
  *(ushort4*)(ob + row * 1024 + t * 4) = pk;
}

extern "C" void kernel_launch(void* const* d_in, const int* in_sizes, int n_in,
                              void* d_out, int out_size, void* d_ws, size_t ws_size,
                              hipStream_t stream) {
  (void)in_sizes; (void)n_in; (void)out_size; (void)ws_size;
  const float* x = (const float*)d_in[0];
  const float* ln1_g = (const float*)d_in[1];
  const float* ln1_b = (const float*)d_in[2];
  const float* lnm_g = (const float*)d_in[3];
  const float* lnm_b = (const float*)d_in[4];
  const float* qkv_w = (const float*)d_in[5];
  const float* qkv_b = (const float*)d_in[6];
  const float* proj_w = (const float*)d_in[7];
  const float* proj_b = (const float*)d_in[8];
  const float* fc1_w = (const float*)d_in[9];
  const float* fc1_b = (const float*)d_in[10];
  const float* fc2_w = (const float*)d_in[11];
  const float* fc2_b = (const float*)d_in[12];
  float* out = (float*)d_out;

  const int M = 4096;
  const int D_ = 1024, MLP_ = 4096, QKV = 3072;

  char* ws = (char*)d_ws;
  bf16_t* h = (bf16_t*)(ws);                       // 8 MB  (dead after qkv gemm)
  bf16_t* qkvb = (bf16_t*)(ws + (8u << 20));       // 24 MB (dead after attn)
  bf16_t* ob = (bf16_t*)(ws + (32u << 20));        // 8 MB  (dead after proj gemm)
  float* x1 = (float*)(ws + (40u << 20));          // 16 MB
  float* li_g = (float*)(ws + (56u << 20));        // 0.5 MB (dead after merge; mb after)
  bf16_t* mb = (bf16_t*)(ws + (57u << 20));        // 7 MB... mb needs 8MB
  float* oa = (float*)(ws + (64u << 20));          // 32 MB attn partials (dead after merge; gb after)
  bf16_t* gb = (bf16_t*)(ws + (64u << 20));        // 32 MB (written by fc1, after oa dead)
  bf16_t* qkv_wt = (bf16_t*)(ws + (96u << 20));    // 6 MB
  bf16_t* proj_wt = (bf16_t*)(ws + (102u << 20));  // 2 MB
  bf16_t* fc1_wt = (bf16_t*)(ws + (104u << 20));   // 8 MB
  bf16_t* fc2_wt = (bf16_t*)(ws + (112u << 20));   // 8 MB
  bf16_t* p_proj = (bf16_t*)(ws);                  // 32 MB (reuses dead h+qkvb)
  bf16_t* p_fc2 = (bf16_t*)(ws);                   // 32 MB (p_proj dead by then)
  // NOTE: mb placed at 120 MB to keep a clean 8 MB region
  mb = (bf16_t*)(ws + (120u << 20));               // 8 MB (total 128 MB)

  wconv_all<<<7168, 256, 0, stream>>>(qkv_w, qkv_wt, proj_w, proj_wt, fc1_w, fc1_wt,
                                      fc2_w, fc2_wt, x, ln1_g, ln1_b, h);
  gemm_kernel<<<dim3(QKV / 128, M / 256), 512, 0, stream>>>(h, qkv_wt, qkv_b, nullptr,
                                                            qkvb, M, QKV, D_, 0);
  attn_kernel<<<1024, 256, 0, stream>>>(qkvb, oa, li_g);
  attn_merge<<<4096, 256, 0, stream>>>(oa, li_g, ob);
  gemm_kernel<<<dim3(D_ / 128, M / 256, 4), 512, 0, stream>>>(ob, proj_wt, nullptr,
                                                              nullptr, p_proj, M, D_,
                                                              D_, 3);
  reduce_ln_kernel<<<M, 256, 0, stream>>>(p_proj, proj_b, x, x1, lnm_g, lnm_b, mb);
  gemm_kernel<<<dim3(MLP_ / 128, M / 256), 512, 0, stream>>>(mb, fc1_wt, fc1_b,
                                                             nullptr, gb, M, MLP_, D_,
                                                             2);
  gemm_kernel<<<dim3(D_ / 128, M / 256, 4), 512, 0, stream>>>(gb, fc2_wt, nullptr,
                                                              nullptr, p_fc2, M, D_,
                                                              MLP_, 3);
  reduce4_kernel<<<4096, 256, 0, stream>>>(p_fc2, fc2_b, x1, out);
}

// Round 12
// 384.611 us; speedup vs baseline: 1.0471x; 1.0164x over previous
//
#include <hip/hip_runtime.h>

typedef __bf16 bf16_t;
typedef bf16_t bf16x4 __attribute__((ext_vector_type(4)));
typedef bf16_t bf16x8 __attribute__((ext_vector_type(8)));
typedef float f32x4 __attribute__((ext_vector_type(4)));
typedef unsigned short u16x8 __attribute__((ext_vector_type(8)));

#define MFMA(a, b, c) __builtin_amdgcn_mfma_f32_16x16x32_bf16(a, b, c, 0, 0, 0)

__device__ inline float exp2_fast(float x) {
  float r;
  asm volatile("v_exp_f32 %0, %1" : "=v"(r) : "v"(x));
  return r;
}

// async global->LDS, 16B/lane; HW dest = wave-uniform base + lane*16
__device__ inline void gll16(const bf16_t* g, bf16_t* l) {
  __builtin_amdgcn_global_load_lds(
      (const __attribute__((address_space(1))) unsigned int*)(g),
      (__attribute__((address_space(3))) unsigned int*)(l), 16, 0, 0);
}

// exact-erf GELU via A&S 7.1.26 poly (|err| < 1.5e-7, invisible under bf16 store)
__device__ inline float gelu_f(float v) {
  float ax = fabsf(v) * 0.70710678118f;
  float t = __builtin_amdgcn_rcpf(1.0f + 0.3275911f * ax);
  float p = ((((1.061405429f * t - 1.453152027f) * t + 1.421413741f) * t -
              0.284496736f) * t + 0.254829592f) * t;
  float e = exp2_fast(-ax * ax * 1.4426950408889634f);
  float erf = 1.0f - p * e;
  erf = v < 0.f ? -erf : erf;
  return 0.5f * v * (1.0f + erf);
}

// ---- fused: weight convert+transpose (blocks 0..3071) + LayerNorm1 (3072..7167) ----
__global__ __launch_bounds__(256) void wconv_all(
    const float* __restrict__ qkv_w, bf16_t* __restrict__ qkv_wt,
    const float* __restrict__ proj_w, bf16_t* __restrict__ proj_wt,
    const float* __restrict__ fc1_w, bf16_t* __restrict__ fc1_wt,
    const float* __restrict__ fc2_w, bf16_t* __restrict__ fc2_wt,
    const float* __restrict__ x, const float* __restrict__ g1,
    const float* __restrict__ b1, bf16_t* __restrict__ h) {
  int id = blockIdx.x;
  if (id >= 3072) {
    long row = id - 3072;
    const float4* xr = (const float4*)(x + row * 1024);
    float4 v = xr[threadIdx.x];
    float s = v.x + v.y + v.z + v.w;
    float s2 = v.x * v.x + v.y * v.y + v.z * v.z + v.w * v.w;
#pragma unroll
    for (int m = 32; m >= 1; m >>= 1) {
      s += __shfl_xor(s, m);
      s2 += __shfl_xor(s2, m);
    }
    __shared__ float red[8];
    int wid = threadIdx.x >> 6;
    if ((threadIdx.x & 63) == 0) {
      red[wid] = s;
      red[4 + wid] = s2;
    }
    __syncthreads();
    s = red[0] + red[1] + red[2] + red[3];
    s2 = red[4] + red[5] + red[6] + red[7];
    float mu = s * (1.f / 1024.f);
    float rs = rsqrtf(s2 * (1.f / 1024.f) - mu * mu + 1e-5f);
    float4 gv = ((const float4*)g1)[threadIdx.x];
    float4 bv = ((const float4*)b1)[threadIdx.x];
    bf16_t o0 = (bf16_t)((v.x - mu) * rs * gv.x + bv.x);
    bf16_t o1 = (bf16_t)((v.y - mu) * rs * gv.y + bv.y);
    bf16_t o2 = (bf16_t)((v.z - mu) * rs * gv.z + bv.z);
    bf16_t o3 = (bf16_t)((v.w - mu) * rs * gv.w + bv.w);
    ushort4 pk;
    pk.x = *(unsigned short*)&o0;
    pk.y = *(unsigned short*)&o1;
    pk.z = *(unsigned short*)&o2;
    pk.w = *(unsigned short*)&o3;
    *(ushort4*)(h + row * 1024 + threadIdx.x * 4) = pk;
    return;
  }
  const float* W;
  bf16_t* Wt;
  int K, N, bx, by;
  if (id < 768) {
    W = qkv_w; Wt = qkv_wt; K = 1024; N = 3072; bx = id % 48; by = id / 48;
  } else if (id < 1024) {
    int l = id - 768;
    W = proj_w; Wt = proj_wt; K = 1024; N = 1024; bx = l % 16; by = l / 16;
  } else if (id < 2048) {
    int l = id - 1024;
    W = fc1_w; Wt = fc1_wt; K = 1024; N = 4096; bx = l % 64; by = l / 64;
  } else {
    int l = id - 2048;
    W = fc2_w; Wt = fc2_wt; K = 4096; N = 1024; bx = l % 16; by = l / 16;
  }
  __shared__ float t[64][65];
  int n0 = bx * 64, k0 = by * 64;
  int tid = threadIdx.x;
  int c4 = tid & 15;
  int r = tid >> 4;
#pragma unroll
  for (int s = 0; s < 4; s++) {
    int k = r + s * 16;
    float4 v = *(const float4*)(W + (long)(k0 + k) * N + n0 + c4 * 4);
    t[k][c4 * 4] = v.x;
    t[k][c4 * 4 + 1] = v.y;
    t[k][c4 * 4 + 2] = v.z;
    t[k][c4 * 4 + 3] = v.w;
  }
  __syncthreads();
  int n = tid >> 2;
  int kc = (tid & 3) * 16;
  ushort4 pk[4];
#pragma unroll
  for (int c = 0; c < 4; c++) {
#pragma unroll
    for (int j = 0; j < 4; j++) {
      bf16_t xq = (bf16_t)t[kc + c * 4 + j][n];
      ((unsigned short*)&pk[c])[j] = *(unsigned short*)&xq;
    }
  }
  bf16_t* dst = Wt + (long)(n0 + n) * K + k0 + kc;
#pragma unroll
  for (int c = 0; c < 4; c++) *(ushort4*)(dst + c * 4) = pk[c];
}

// ------- GEMM: 256x128 tile, 512 thr, 3-stage pipe, XCD-grouped 1-D grid -------
// Grid = nbn*16*nz blocks, 1-D. blockIdx&7 -> XCD (verified round-robin mapping);
// each XCD owns (nbn*nz/8) column-groups -> its B tiles stay resident in its 4MB L2.
// epi 0: bf16 = acc+bias ; 1: f32 = acc+bias+resid ; 2: bf16 = gelu(acc+bias)
// epi 3: bf16 partial = acc (split-K chunk kz)
#define STAGE_PTR(DA, DB, k0)                 \
  gll16(ga + (k0), DA + w * 512);             \
  gll16(ga + (k0) + astep, DA + 4096 + w * 512); \
  gll16(gb + (k0), DB + w * 512);

#define COMPUTE(LA, LB)                                                \
  {                                                                    \
    bf16x8 af[4], bfr[4];                                              \
    _Pragma("unroll") for (int mt = 0; mt < 4; mt++) af[mt] =          \
        *(const bf16x8*)(LA + (wm + mt * 16 + l15) * 32 + quad * 8);   \
    _Pragma("unroll") for (int nt = 0; nt < 4; nt++) bfr[nt] =         \
        *(const bf16x8*)(LB + (wn + nt * 16 + l15) * 32 + quad * 8);   \
    _Pragma("unroll") for (int mt = 0; mt < 4; mt++)                   \
        _Pragma("unroll") for (int nt = 0; nt < 4; nt++) acc[mt][nt] = \
            MFMA(af[mt], bfr[nt], acc[mt][nt]);                        \
  }

#define WB3 asm volatile("s_waitcnt vmcnt(3)\ns_barrier" ::: "memory")
#define WB0 asm volatile("s_waitcnt vmcnt(0)\ns_barrier" ::: "memory")

__global__ __launch_bounds__(512, 4) void gemm_kernel(
    const bf16_t* __restrict__ A, const bf16_t* __restrict__ Bt,
    const float* __restrict__ bias, const float* __restrict__ resid,
    void* __restrict__ Cout, int M, int N, int K, int epi, int nbn, int nz) {
  __shared__ bf16_t lA0[256 * 32], lB0[128 * 32];
  __shared__ bf16_t lA1[256 * 32], lB1[128 * 32];
  __shared__ bf16_t lA2[256 * 32], lB2[128 * 32];
  int tid = threadIdx.x;
  // XCD-grouped decode: xcd = id&7, column-group g fixed per XCD band
  int id = blockIdx.x;
  int xcd = id & 7;
  int slot = id >> 3;
  int gpx = (nbn * nz) >> 3;  // column-groups per XCD (must divide evenly)
  int g = xcd * gpx + (slot >> 4);
  int bm = slot & 15;
  int bn = g / nz;
  int kz = g % nz;
  int kchunk = K / nz;
  int kbeg = kz * kchunk, kend = kbeg + kchunk;

  int lane = tid & 63, w = tid >> 6;
  int quad = lane >> 4, l15 = lane & 15;
  int wm = (w & 3) * 64, wn = (w >> 2) * 64;

  f32x4 acc[4][4];
#pragma unroll
  for (int i = 0; i < 4; i++)
#pragma unroll
    for (int j = 0; j < 4; j++) acc[i][j] = (f32x4){0.f, 0.f, 0.f, 0.f};

  const bf16_t* ga = A + (long)(bm * 256 + w * 16 + (lane >> 2)) * K + (lane & 3) * 8;
  const bf16_t* gb = Bt + (long)(bn * 128 + w * 16 + (lane >> 2)) * K + (lane & 3) * 8;
  long astep = (long)128 * K;

  int nit = (kend - kbeg) >> 5;
  bf16_t *A0 = lA0, *A1 = lA1, *A2 = lA2;
  bf16_t *B0 = lB0, *B1 = lB1, *B2 = lB2;
  STAGE_PTR(A0, B0, kbeg);
  STAGE_PTR(A1, B1, kbeg + 32);
  for (int i = 0; i < nit; i++) {
    if (i + 1 < nit) { WB3; } else { WB0; }
    if (i + 2 < nit) {
      int ks = kbeg + (i + 2) * 32;
      STAGE_PTR(A2, B2, ks);
    }
    COMPUTE(A0, B0);
    bf16_t* t;
    t = A0; A0 = A1; A1 = A2; A2 = t;
    t = B0; B0 = B1; B1 = B2; B2 = t;
  }

#pragma unroll
  for (int mt = 0; mt < 4; mt++) {
#pragma unroll
    for (int r = 0; r < 4; r++) {
      long row = bm * 256 + wm + mt * 16 + quad * 4 + r;
#pragma unroll
      for (int nt = 0; nt < 4; nt++) {
        int col = bn * 128 + wn + nt * 16 + l15;
        long idx = row * N + col;
        if (epi == 3) {
          ((bf16_t*)Cout)[(long)kz * M * N + idx] = (bf16_t)acc[mt][nt][r];
        } else {
          float v = acc[mt][nt][r] + bias[col];
          if (epi == 1) {
            ((float*)Cout)[idx] = v + resid[idx];
          } else if (epi == 2) {
            ((bf16_t*)Cout)[idx] = (bf16_t)gelu_f(v);
          } else {
            ((bf16_t*)Cout)[idx] = (bf16_t)v;
          }
        }
      }
    }
  }
}

// ---- fused: x1 = p0..p3+bias+resid ; mb = LayerNorm(x1)*g+b ----
__global__ __launch_bounds__(256) void reduce_ln_kernel(
    const bf16_t* __restrict__ p, const float* __restrict__ bias,
    const float* __restrict__ resid, float* __restrict__ x1,
    const float* __restrict__ g, const float* __restrict__ bb,
    bf16_t* __restrict__ mb) {
  const long MN = (long)4096 * 1024;
  long row = blockIdx.x;
  int t = threadIdx.x;
  bf16x4 a0 = *(const bf16x4*)(p + row * 1024 + t * 4);
  bf16x4 a1 = *(const bf16x4*)(p + MN + row * 1024 + t * 4);
  bf16x4 a2 = *(const bf16x4*)(p + 2 * MN + row * 1024 + t * 4);
  bf16x4 a3 = *(const bf16x4*)(p + 3 * MN + row * 1024 + t * 4);
  float4 r = ((const float4*)(resid + row * 1024))[t];
  float4 bv = ((const float4*)bias)[t];
  float4 v;
  v.x = (float)a0[0] + (float)a1[0] + (float)a2[0] + (float)a3[0] + r.x + bv.x;
  v.y = (float)a0[1] + (float)a1[1] + (float)a2[1] + (float)a3[1] + r.y + bv.y;
  v.z = (float)a0[2] + (float)a1[2] + (float)a2[2] + (float)a3[2] + r.z + bv.z;
  v.w = (float)a0[3] + (float)a1[3] + (float)a2[3] + (float)a3[3] + r.w + bv.w;
  ((float4*)(x1 + row * 1024))[t] = v;
  float s = v.x + v.y + v.z + v.w;
  float s2 = v.x * v.x + v.y * v.y + v.z * v.z + v.w * v.w;
#pragma unroll
  for (int m = 32; m >= 1; m >>= 1) {
    s += __shfl_xor(s, m);
    s2 += __shfl_xor(s2, m);
  }
  __shared__ float red[8];
  int wid = t >> 6;
  if ((t & 63) == 0) {
    red[wid] = s;
    red[4 + wid] = s2;
  }
  __syncthreads();
  s = red[0] + red[1] + red[2] + red[3];
  s2 = red[4] + red[5] + red[6] + red[7];
  float mu = s * (1.f / 1024.f);
  float rs = rsqrtf(s2 * (1.f / 1024.f) - mu * mu + 1e-5f);
  float4 gv = ((const float4*)g)[t];
  float4 b2 = ((const float4*)bb)[t];
  bf16_t o0 = (bf16_t)((v.x - mu) * rs * gv.x + b2.x);
  bf16_t o1 = (bf16_t)((v.y - mu) * rs * gv.y + b2.y);
  bf16_t o2 = (bf16_t)((v.z - mu) * rs * gv.z + b2.z);
  bf16_t o3 = (bf16_t)((v.w - mu) * rs * gv.w + b2.w);
  ushort4 pk;
  pk.x = *(unsigned short*)&o0;
  pk.y = *(unsigned short*)&o1;
  pk.z = *(unsigned short*)&o2;
  pk.w = *(unsigned short*)&o3;
  *(ushort4*)(mb + row * 1024 + t * 4) = pk;
}

// ---- fc2 reduce: out = p0..p3 + bias + resid (fp32) ----
__global__ __launch_bounds__(256) void reduce4_kernel(const bf16_t* __restrict__ p,
                                                      const float* __restrict__ bias,
                                                      const float* __restrict__ resid,
                                                      float* __restrict__ out) {
  long i = (long)blockIdx.x * 256 + threadIdx.x;
  const long MN = (long)4096 * 1024;
  bf16x4 a0 = *(const bf16x4*)(p + i * 4);
  bf16x4 a1 = *(const bf16x4*)(p + MN + i * 4);
  bf16x4 a2 = *(const bf16x4*)(p + 2 * MN + i * 4);
  bf16x4 a3 = *(const bf16x4*)(p + 3 * MN + i * 4);
  float4 r = ((const float4*)resid)[i];
  float4 bv = ((const float4*)bias)[i & 255];
  float4 o;
  o.x = (float)a0[0] + (float)a1[0] + (float)a2[0] + (float)a3[0] + r.x + bv.x;
  o.y = (float)a0[1] + (float)a1[1] + (float)a2[1] + (float)a3[1] + r.y + bv.y;
  o.z = (float)a0[2] + (float)a1[2] + (float)a2[2] + (float)a3[2] + r.z + bv.z;
  o.w = (float)a0[3] + (float)a1[3] + (float)a2[3] + (float)a3[3] + r.w + bv.w;
  ((float4*)out)[i] = o;
}

// ------- Flash attention: 128 q/block, pipelined K/V staging, XCD-swizzled -------
#define LDV 72

__global__ __launch_bounds__(256) void attn_kernel(const bf16_t* __restrict__ qkv,
                                                   bf16_t* __restrict__ o) {
  const int LD = 3072;
  int id = blockIdx.x;  // 512 blocks
  int within = id >> 3;
  int bh = (id & 7) * 4 + (within >> 4);
  int qt = within & 15;
  int h = bh & 15, b = bh >> 4;

  int tid = threadIdx.x, w = tid >> 6, lane = tid & 63;
  int quad = lane >> 4, l15 = lane & 15;
  int qrow = qt * 128 + w * 32;
  const bf16_t* base = qkv + (long)b * 2048 * LD + h * 64;
  const bf16_t* Qp = base;
  const bf16_t* Kp = base + 1024;
  const bf16_t* Vp = base + 2048;

  __shared__ bf16_t lK[2][64 * 64];
  __shared__ bf16_t lV[2][64 * LDV];
  __shared__ bf16_t lP[4][32 * LDV];
  bf16_t* myp = lP[w];

  const bf16_t* kg =
      Kp + (long)(w * 16 + (lane >> 3)) * LD + (((lane & 7) ^ (lane >> 3)) & 7) * 8;
  int kk = tid & 31;
  int d0 = (tid >> 5) * 8;
  const bf16_t* vg = Vp + (long)(2 * kk) * LD + d0;

  gll16(kg, lK[0] + w * 1024);
  gll16(kg + 8 * (long)LD, lK[0] + w * 1024 + 512);
  u16x8 va = *(const u16x8*)(vg);
  u16x8 vb = *(const u16x8*)(vg + LD);

  // Q pre-scaled by 0.125*log2(e): softmax exp becomes bare exp2 of the score
  const float c2 = 0.18033688011112042f;
  bf16x8 qf[2][2];
#pragma unroll
  for (int qi = 0; qi < 2; qi++)
#pragma unroll
    for (int d = 0; d < 2; d++) {
      bf16x8 q0 =
          *(const bf16x8*)(Qp + (long)(qrow + qi * 16 + l15) * LD + d * 32 + quad * 8);
#pragma unroll
      for (int j = 0; j < 8; j++) qf[qi][d][j] = (bf16_t)((float)q0[j] * c2);
    }

  f32x4 oacc[2][4];
#pragma unroll
  for (int qi = 0; qi < 2; qi++)
#pragma unroll
    for (int t = 0; t < 4; t++) oacc[qi][t] = (f32x4){0.f, 0.f, 0.f, 0.f};
  float li_p[2][4] = {{0.f, 0.f, 0.f, 0.f}, {0.f, 0.f, 0.f, 0.f}};

  int sw0 = (quad ^ l15) & 7;
  int sw1 = ((quad + 4) ^ l15) & 7;

  for (int it = 0; it < 32; it++) {
    int cur = it & 1, nxt = cur ^ 1;
    asm volatile("s_waitcnt vmcnt(0)\ns_barrier" ::: "memory");
    unsigned int* lvw = (unsigned int*)lV[cur];
#pragma unroll
    for (int j = 0; j < 8; j++)
      lvw[(d0 + j) * (LDV / 2) + kk] = (unsigned int)va[j] | ((unsigned int)vb[j] << 16);
    u16x8 va_n = va, vb_n = vb;
    if (it + 1 < 32) {
      long koff2 = (long)(it + 1) * 64 * LD;
      gll16(kg + koff2, lK[nxt] + w * 1024);
      gll16(kg + koff2 + 8 * (long)LD, lK[nxt] + w * 1024 + 512);
      va_n = *(const u16x8*)(vg + koff2);
      vb_n = *(const u16x8*)(vg + koff2 + LD);
    }
    asm volatile("s_waitcnt lgkmcnt(0)\ns_barrier" ::: "memory");

    bf16x8 kf[4][2];
#pragma unroll
    for (int st = 0; st < 4; st++) {
      const bf16_t* krow = lK[cur] + (st * 16 + l15) * 64;
      kf[st][0] = *(const bf16x8*)(krow + sw0 * 8);
      kf[st][1] = *(const bf16x8*)(krow + sw1 * 8);
    }
    f32x4 s[2][4];
#pragma unroll
    for (int qi = 0; qi < 2; qi++)
#pragma unroll
      for (int st = 0; st < 4; st++) {
        f32x4 z = (f32x4){0.f, 0.f, 0.f, 0.f};
        z = MFMA(qf[qi][0], kf[st][0], z);
        s[qi][st] = MFMA(qf[qi][1], kf[st][1], z);
      }

#pragma unroll
    for (int qi = 0; qi < 2; qi++)
#pragma unroll
      for (int st = 0; st < 4; st++)
#pragma unroll
        for (int r = 0; r < 4; r++) {
          float p = exp2_fast(s[qi][st][r]);
          s[qi][st][r] = p;
          li_p[qi][r] += p;
        }

#pragma unroll
    for (int qi = 0; qi < 2; qi++)
#pragma unroll
      for (int r = 0; r < 4; r++)
#pragma unroll
        for (int st = 0; st < 4; st++)
          myp[(qi * 16 + quad * 4 + r) * LDV + st * 16 + l15] = (bf16_t)s[qi][st][r];
    asm volatile("s_waitcnt lgkmcnt(0)" ::: "memory");

    bf16x8 pa[2][2];
#pragma unroll
    for (int qi = 0; qi < 2; qi++) {
      pa[qi][0] = *(const bf16x8*)(myp + (qi * 16 + l15) * LDV + quad * 8);
      pa[qi][1] = *(const bf16x8*)(myp + (qi * 16 + l15) * LDV + 32 + quad * 8);
    }
#pragma unroll
    for (int t = 0; t < 4; t++) {
      const bf16_t* vr = lV[cur] + (t * 16 + l15) * LDV + quad * 8;
      bf16x8 v0 = *(const bf16x8*)(vr);
      bf16x8 v1 = *(const bf16x8*)(vr + 32);
#pragma unroll
      for (int qi = 0; qi < 2; qi++) {
        oacc[qi][t] = MFMA(pa[qi][0], v0, oacc[qi][t]);
        oacc[qi][t] = MFMA(pa[qi][1], v1, oacc[qi][t]);
      }
    }
    va = va_n;
    vb = vb_n;
  }

#pragma unroll
  for (int qi = 0; qi < 2; qi++) {
    float li[4];
#pragma unroll
    for (int r = 0; r < 4; r++) {
      float s = li_p[qi][r];
#pragma unroll
      for (int x = 8; x >= 1; x >>= 1) s += __shfl_xor(s, x);
      li[r] = s;
    }
#pragma unroll
    for (int t = 0; t < 4; t++)
#pragma unroll
      for (int r = 0; r < 4; r++) {
        long q = qrow + qi * 16 + quad * 4 + r;
        o[((long)b * 2048 + q) * 1024 + h * 64 + t * 16 + l15] =
            (bf16_t)(oacc[qi][t][r] / li[r]);
      }
  }
}

extern "C" void kernel_launch(void* const* d_in, const int* in_sizes, int n_in,
                              void* d_out, int out_size, void* d_ws, size_t ws_size,
                              hipStream_t stream) {
  (void)in_sizes; (void)n_in; (void)out_size; (void)ws_size;
  const float* x = (const float*)d_in[0];
  const float* ln1_g = (const float*)d_in[1];
  const float* ln1_b = (const float*)d_in[2];
  const float* lnm_g = (const float*)d_in[3];
  const float* lnm_b = (const float*)d_in[4];
  const float* qkv_w = (const float*)d_in[5];
  const float* qkv_b = (const float*)d_in[6];
  const float* proj_w = (const float*)d_in[7];
  const float* proj_b = (const float*)d_in[8];
  const float* fc1_w = (const float*)d_in[9];
  const float* fc1_b = (const float*)d_in[10];
  const float* fc2_w = (const float*)d_in[11];
  const float* fc2_b = (const float*)d_in[12];
  float* out = (float*)d_out;

  const int M = 4096;
  const int D_ = 1024, MLP_ = 4096, QKV = 3072;

  char* ws = (char*)d_ws;
  bf16_t* h = (bf16_t*)(ws);                       // 8 MB  (dead after qkv gemm)
  bf16_t* qkvb = (bf16_t*)(ws + (8u << 20));       // 24 MB (dead after attn)
  bf16_t* ob = (bf16_t*)(ws + (32u << 20));        // 8 MB  (dead after proj gemm)
  float* x1 = (float*)(ws + (40u << 20));          // 16 MB
  bf16_t* mb = (bf16_t*)(ws + (56u << 20));        // 8 MB
  bf16_t* gb = (bf16_t*)(ws + (64u << 20));        // 32 MB
  bf16_t* qkv_wt = (bf16_t*)(ws + (96u << 20));    // 6 MB
  bf16_t* proj_wt = (bf16_t*)(ws + (102u << 20));  // 2 MB
  bf16_t* fc1_wt = (bf16_t*)(ws + (104u << 20));   // 8 MB
  bf16_t* fc2_wt = (bf16_t*)(ws + (112u << 20));   // 8 MB
  bf16_t* p_proj = (bf16_t*)(ws);                  // 32 MB (reuses dead h+qkvb)
  bf16_t* p_fc2 = (bf16_t*)(ws);                   // 32 MB (p_proj dead by then)

  wconv_all<<<7168, 256, 0, stream>>>(qkv_w, qkv_wt, proj_w, proj_wt, fc1_w, fc1_wt,
                                      fc2_w, fc2_wt, x, ln1_g, ln1_b, h);
  // qkv: nbn=24 (3 cols/XCD), nz=1 -> 384 blocks
  gemm_kernel<<<384, 512, 0, stream>>>(h, qkv_wt, qkv_b, nullptr, qkvb, M, QKV, D_, 0,
                                       24, 1);
  attn_kernel<<<512, 256, 0, stream>>>(qkvb, ob);
  // proj: nbn=8, nz=4 (1 col x 4 k-chunks per XCD) -> 512 blocks, bf16 partials
  gemm_kernel<<<512, 512, 0, stream>>>(ob, proj_wt, nullptr, nullptr, p_proj, M, D_,
                                       D_, 3, 8, 4);
  reduce_ln_kernel<<<M, 256, 0, stream>>>(p_proj, proj_b, x, x1, lnm_g, lnm_b, mb);
  // fc1: nbn=32 (4 cols/XCD), nz=1 -> 512 blocks, gelu epilogue
  gemm_kernel<<<512, 512, 0, stream>>>(mb, fc1_wt, fc1_b, nullptr, gb, M, MLP_, D_, 2,
                                       32, 1);
  // fc2: nbn=8, nz=4 -> 512 blocks, bf16 partials
  gemm_kernel<<<512, 512, 0, stream>>>(gb, fc2_wt, nullptr, nullptr, p_fc2, M, D_,
                                       MLP_, 3, 8, 4);
  reduce4_kernel<<<4096, 256, 0, stream>>>(p_fc2, fc2_b, x1, out);
}